// Round 6
// baseline (247.771 us; speedup 1.0000x reference)
//
#include <hip/hip_runtime.h>

// ---------------------------------------------------------------------------
// MoE cross-attention decoder layer on MI355X (gfx950), bf16 MFMA pipeline.
// R6: persistent-W QKV GEMM — each block pins one (expert, Q/K/V, col-half)
// weight tile (64 KB) in LDS for its lifetime and streams 64-row A-tiles
// (8 KB/iter, double-buffered) over its M-range. Intensity 262 FLOP/staged-B
// (was 64). Epilogue ni-inner so 64B sectors merge (R5 write-amp fix).
// Attention/cvt/combine/finalize/gemm_o unchanged from R5.
// ---------------------------------------------------------------------------

typedef __bf16 bf16x8 __attribute__((ext_vector_type(8)));
typedef float f32x4 __attribute__((ext_vector_type(4)));
typedef unsigned int u32x4 __attribute__((ext_vector_type(4)));
typedef unsigned int u32x2 __attribute__((ext_vector_type(2)));
typedef unsigned short u16x4 __attribute__((ext_vector_type(4)));
typedef unsigned short us;

__device__ __forceinline__ us f2bf(float f) {
    unsigned u = __builtin_bit_cast(unsigned, f);
    u += 0x7FFFu + ((u >> 16) & 1u);
    return (us)(u >> 16);
}

__device__ __forceinline__ float bf2f(us v) {
    unsigned u = ((unsigned)v) << 16;
    return __builtin_bit_cast(float, u);
}

__device__ __forceinline__ bf16x8 ld_bf8(const us* p) {
    return __builtin_bit_cast(bf16x8, *reinterpret_cast<const u32x4*>(p));
}

__device__ __forceinline__ void gld_lds16(const us* g, us* l) {
    __builtin_amdgcn_global_load_lds(
        (const __attribute__((address_space(1))) unsigned int*)g,
        (__attribute__((address_space(3))) unsigned int*)l, 16, 0, 0);
}

// ---------------- fused converts: one launch -------------------------------
__launch_bounds__(256)
__global__ void cvt_all(const float* __restrict__ tgt, const float* __restrict__ qpos,
                        const float* __restrict__ mem, const float* __restrict__ pos,
                        const float* __restrict__ w_in, const float* __restrict__ w_out,
                        us* __restrict__ Aq, us* __restrict__ Ak, us* __restrict__ Av,
                        us* __restrict__ Wb, us* __restrict__ WOb)
{
    const int bid = blockIdx.x;
    const int tid = threadIdx.x;
    if (bid < 400) {
        int i = bid * 256 + tid;
        f32x4 a = reinterpret_cast<const f32x4*>(tgt)[i];
        f32x4 b = reinterpret_cast<const f32x4*>(qpos)[i];
        u16x4 r;
#pragma unroll
        for (int j = 0; j < 4; ++j) r[j] = f2bf(a[j] + b[j]);
        reinterpret_cast<u16x4*>(Aq)[i] = r;
    } else if (bid < 4496) {
        int i = (bid - 400) * 256 + tid;
        f32x4 m = reinterpret_cast<const f32x4*>(mem)[i];
        f32x4 p = reinterpret_cast<const f32x4*>(pos)[i];
        u16x4 rk, rv;
#pragma unroll
        for (int j = 0; j < 4; ++j) { rk[j] = f2bf(m[j] + p[j]); rv[j] = f2bf(m[j]); }
        reinterpret_cast<u16x4*>(Ak)[i] = rk;
        reinterpret_cast<u16x4*>(Av)[i] = rv;
    } else if (bid < 5456) {
        int i = (bid - 4496) * 256 + tid;
        f32x4 a = reinterpret_cast<const f32x4*>(w_in)[i];
        u16x4 r;
#pragma unroll
        for (int j = 0; j < 4; ++j) r[j] = f2bf(a[j]);
        reinterpret_cast<u16x4*>(Wb)[i] = r;
    } else {
        int i = (bid - 5456) * 256 + tid;
        f32x4 a = reinterpret_cast<const f32x4*>(w_out)[i];
        u16x4 r;
#pragma unroll
        for (int j = 0; j < 4; ++j) r[j] = f2bf(a[j]);
        reinterpret_cast<u16x4*>(WOb)[i] = r;
    }
}

// ---------------- persistent-W QKV GEMM ------------------------------------
// Block = one (expert, matrix, 128-col half) + an M-range of 64-row tiles.
// Ws: 128 rows x 256 K resident (64 KB); A: 64 x 64 double-buffered (2x8KB).
// XOR seg swizzles (global-side) keep gld_lds lane-linear and LDS frag reads
// conflict-free. Transposed mfma(bf, af): C[l15 = A-row][quad*4+r = W-col]
// -> packed 8B stores, ni-inner so sector halves merge in L2.
__launch_bounds__(256)
__global__ void gemm_qkv_p(const us* __restrict__ Aq, const us* __restrict__ Ak,
                           const us* __restrict__ Av, const us* __restrict__ Wb,
                           const float* __restrict__ b_in,
                           us* __restrict__ Qb, us* __restrict__ Kb, us* __restrict__ Vb)
{
    __shared__ us Ws[128 * 256];     // 64 KB, row stride 512 B
    __shared__ us Asb[2][64 * 64];   // 2 x 8 KB, row stride 128 B
    const int tid  = threadIdx.x;
    const int lane = tid & 63;
    const int w    = tid >> 6;       // 0..3
    const int l15  = lane & 15;
    const int quad = lane >> 4;

    const int bid = blockIdx.x;
    const us* A; us* Cout; const float* bias; float scale; int t0, t1;
    const us* Wg;
    if (bid < 240) {                 // K/V: 20 combos x 12 sub-blocks
        const int c = bid / 12, sub = bid % 12;
        const int e = c >> 2, mh = c & 3;
        const int mat = (mh >> 1) + 1;   // 1=K, 2=V
        const int half = mh & 1;
        A     = (mat == 1) ? Ak : Av;
        Wg    = Wb + (size_t)e * 196608 + mat * 65536 + half * 32768;
        bias  = b_in + e * 768 + mat * 256 + half * 128;
        Cout  = ((mat == 1) ? Kb : Vb) + (size_t)e * 4194304 + half * 128;
        scale = 1.0f;
        t0 = sub * 22; t1 = min(256, t0 + 22);
    } else {                         // Q: 10 combos x 2 sub-blocks
        const int q = bid - 240;
        const int c = q >> 1, sub = q & 1;
        const int e = c >> 1, half = c & 1;
        A     = Aq;
        Wg    = Wb + (size_t)e * 196608 + half * 32768;
        bias  = b_in + e * 768 + half * 128;
        Cout  = Qb + (size_t)e * 409600 + half * 128;
        scale = 0.17677669529663687f;
        t0 = sub * 13; t1 = min(25, t0 + 13);
    }

    // ---- stage W once: LDS[row][s] = G[row][(s&24)|((s&7)^(row&7))] -------
#pragma unroll
    for (int k = 0; k < 16; ++k) {
        const int flat = k * 256 + tid;          // 16B-seg index 0..4095
        const int row = flat >> 5, s = flat & 31;
        const int gs = (s & 24) | ((s & 7) ^ (row & 7));
        gld_lds16(Wg + (size_t)row * 256 + gs * 8, &Ws[flat * 8]);
    }

    const int srow = lane >> 3;      // A-staging: row-in-chunk, seg
    const int aseg = lane & 7;
    auto stageA = [&](int buf, int t, int kt) {
#pragma unroll
        for (int cc = 0; cc < 2; ++cc) {
            const int c = w + cc * 4;            // chunk of 8 rows
            const int row = c * 8 + srow;
            const int gs = aseg ^ srow;          // row&7 == srow
            gld_lds16(A + (size_t)(t * 64 + row) * 256 + kt * 64 + gs * 8,
                      &Asb[buf][c * 512 + lane * 8]);
        }
    };

    stageA(0, t0, 0);
    __syncthreads();

    f32x4 acc[4][2];
    const int total = (t1 - t0) * 4;
    int buf = 0;
    for (int it = 0; it < total; ++it) {
        const int t  = t0 + (it >> 2);
        const int kt = it & 3;
        if (it + 1 < total)
            stageA(buf ^ 1, t0 + ((it + 1) >> 2), (it + 1) & 3);
        if (kt == 0) {
#pragma unroll
            for (int mi = 0; mi < 4; ++mi)
#pragma unroll
                for (int ni = 0; ni < 2; ++ni) acc[mi][ni] = f32x4{};
        }
#pragma unroll
        for (int kh = 0; kh < 2; ++kh) {
            bf16x8 af[4], bf[2];
#pragma unroll
            for (int mi = 0; mi < 4; ++mi) {
                const int row = mi * 16 + l15;
                const int seg = (kh * 4 + quad) ^ (row & 7);
                af[mi] = ld_bf8(&Asb[buf][row * 64 + seg * 8]);
            }
#pragma unroll
            for (int ni = 0; ni < 2; ++ni) {
                const int col = w * 32 + ni * 16 + l15;
                const int seg = kt * 8 + kh * 4 + quad;     // of 32 per row
                const int sw = (seg & 24) | ((seg & 7) ^ (col & 7));
                bf[ni] = ld_bf8(&Ws[col * 256 + sw * 8]);
            }
#pragma unroll
            for (int mi = 0; mi < 4; ++mi)
#pragma unroll
                for (int ni = 0; ni < 2; ++ni)
                    acc[mi][ni] = __builtin_amdgcn_mfma_f32_16x16x32_bf16(bf[ni], af[mi], acc[mi][ni], 0, 0, 0);
        }
        if (kt == 3) {  // epilogue for tile t; ni-inner => 64B sector merged
#pragma unroll
            for (int mi = 0; mi < 4; ++mi) {
                const int row = t * 64 + mi * 16 + l15;
                us* cp = Cout + (size_t)row * 256;
#pragma unroll
                for (int ni = 0; ni < 2; ++ni) {
                    const int colb = w * 32 + ni * 16 + quad * 4;
                    const f32x4 b4 = *reinterpret_cast<const f32x4*>(bias + colb);
                    u32x2 pk;
                    pk[0] = (unsigned)f2bf((acc[mi][ni][0] + b4[0]) * scale)
                          | ((unsigned)f2bf((acc[mi][ni][1] + b4[1]) * scale) << 16);
                    pk[1] = (unsigned)f2bf((acc[mi][ni][2] + b4[2]) * scale)
                          | ((unsigned)f2bf((acc[mi][ni][3] + b4[3]) * scale) << 16);
                    *reinterpret_cast<u32x2*>(cp + colb) = pk;
                }
            }
        }
        __syncthreads();  // drain prefetch (overlapped) + WAR on buf
        buf ^= 1;
    }
}

// ---------------- GEMM body for out-proj (R5 pattern) ----------------------
template <bool BF16OUT>
__device__ __forceinline__ void gemm_body(const us* __restrict__ A,
                                          const us* __restrict__ W,
                                          const float* __restrict__ bias,
                                          void* __restrict__ Cout,
                                          float scale, int M)
{
    const int row0 = blockIdx.x * 128;
    const int col0 = blockIdx.y * 128;
    __shared__ us As[2 * 8192];
    __shared__ us Bs[2 * 8192];
    const int tid  = threadIdx.x;
    const int lane = tid & 63;
    const int w    = tid >> 6;
    const int l15  = lane & 15;
    const int quad = lane >> 4;
    const int wm   = (w >> 1) * 64;
    const int wn   = (w & 1) * 64;
    const int srow = lane >> 3;
    const int gofs = ((lane & 7) ^ srow) * 8;

#pragma unroll
    for (int cc = 0; cc < 4; ++cc) {
        const int c = w * 4 + cc;
        const int row = c * 8 + srow;
        gld_lds16(A + (size_t)(row0 + row) * 256 + gofs, &As[c * 512]);
        gld_lds16(W + (size_t)(col0 + row) * 256 + gofs, &Bs[c * 512]);
    }
    __syncthreads();

    f32x4 acc[4][4] = {};

#pragma unroll
    for (int kt = 0; kt < 4; ++kt) {
        const int cur = (kt & 1) * 8192;
        if (kt < 3) {
            const int nxt = ((kt + 1) & 1) * 8192;
            const int k0 = (kt + 1) * 64;
#pragma unroll
            for (int cc = 0; cc < 4; ++cc) {
                const int c = w * 4 + cc;
                const int row = c * 8 + srow;
                gld_lds16(A + (size_t)(row0 + row) * 256 + k0 + gofs, &As[nxt + c * 512]);
                gld_lds16(W + (size_t)(col0 + row) * 256 + k0 + gofs, &Bs[nxt + c * 512]);
            }
        }
#pragma unroll
        for (int kh = 0; kh < 2; ++kh) {
            bf16x8 af[4], bf[4];
#pragma unroll
            for (int mi = 0; mi < 4; ++mi) {
                const int row = wm + mi * 16 + l15;
                const int seg = (kh * 4 + quad) ^ (row & 7);
                af[mi] = ld_bf8(&As[cur + row * 64 + seg * 8]);
            }
#pragma unroll
            for (int ni = 0; ni < 4; ++ni) {
                const int col = wn + ni * 16 + l15;
                const int seg = (kh * 4 + quad) ^ (col & 7);
                bf[ni] = ld_bf8(&Bs[cur + col * 64 + seg * 8]);
            }
#pragma unroll
            for (int mi = 0; mi < 4; ++mi)
#pragma unroll
                for (int ni = 0; ni < 4; ++ni)
                    acc[mi][ni] = __builtin_amdgcn_mfma_f32_16x16x32_bf16(bf[ni], af[mi], acc[mi][ni], 0, 0, 0);
        }
        if (kt < 3) __syncthreads();
    }

#pragma unroll
    for (int mi = 0; mi < 4; ++mi) {
#pragma unroll
        for (int ni = 0; ni < 4; ++ni) {   // ni-inner: sector halves adjacent
            const int colb = col0 + wn + ni * 16 + quad * 4;
            const f32x4 b4 = *reinterpret_cast<const f32x4*>(bias + colb);
            const int row = row0 + wm + mi * 16 + l15;
            if (row < M) {
                if constexpr (BF16OUT) {
                    u32x2 pk;
                    pk[0] = (unsigned)f2bf((acc[mi][ni][0] + b4[0]) * scale)
                          | ((unsigned)f2bf((acc[mi][ni][1] + b4[1]) * scale) << 16);
                    pk[1] = (unsigned)f2bf((acc[mi][ni][2] + b4[2]) * scale)
                          | ((unsigned)f2bf((acc[mi][ni][3] + b4[3]) * scale) << 16);
                    *reinterpret_cast<u32x2*>(reinterpret_cast<us*>(Cout) + (size_t)row * 256 + colb) = pk;
                } else {
                    f32x4 v;
#pragma unroll
                    for (int r = 0; r < 4; ++r) v[r] = (acc[mi][ni][r] + b4[r]) * scale;
                    *reinterpret_cast<f32x4*>(reinterpret_cast<float*>(Cout) + (size_t)row * 256 + colb) = v;
                }
            }
        }
    }
}

__launch_bounds__(256)
__global__ void gemm_o(const us* __restrict__ CTXb, const us* __restrict__ WOb,
                       const float* __restrict__ b_out, float* __restrict__ OUTf)
{
    const int e = blockIdx.z;
    gemm_body<false>(CTXb + (size_t)e * 409600, WOb + (size_t)e * 65536,
                     b_out + (size_t)e * 256, OUTf + (size_t)e * 409600, 1.0f, 1600);
}

// ---------------- split-K attention (unchanged from R4) --------------------
__device__ __forceinline__ int vrow(int d) { return d * 264 + 8 * (d >> 3); }

__launch_bounds__(512)
__global__ void attn(const us* __restrict__ Qb, const us* __restrict__ Kb,
                     const us* __restrict__ Vb, us* __restrict__ PO,
                     float* __restrict__ PL)
{
    const int h = blockIdx.x;
    const int z = blockIdx.y;
    const int s = blockIdx.z;
    const int e = z >> 4, b = z & 15;
    const int tid  = threadIdx.x;
    const int w    = tid >> 6;
    const int lane = tid & 63;
    const int l15  = lane & 15, quad = lane >> 4;
    __shared__ us Ks[256 * 32];
    __shared__ us Vs[8464];
    __shared__ us Ps[7][16 * 40];

    const int key0 = s * 256;
    {
        const int kl  = lane >> 2;
        const int seg = lane & 3;
        const us* kg = Kb + ((size_t)((e * 1024 + key0 + w * 16 + kl) * 16 + b)) * 256
                          + h * 32 + seg * 8;
        gld_lds16(kg, &Ks[w * 512]);
        gld_lds16(kg + (size_t)128 * 16 * 256, &Ks[4096 + w * 512]);

        const int kv = tid >> 2;
        const int sg = tid & 3;
        const us* vg = Vb + ((size_t)((e * 1024 + key0 + kv) * 16 + b)) * 256
                          + h * 32 + sg * 8;
        u32x4 v0 = *reinterpret_cast<const u32x4*>(vg);
        u32x4 v1 = *reinterpret_cast<const u32x4*>(vg + (size_t)128 * 16 * 256);
#pragma unroll
        for (int j = 0; j < 4; ++j) {
            const int d0 = sg * 8 + 2 * j;
            const int e0 = vrow(d0);
            const int e1 = e0 + 264;
            Vs[e0 + kv]       = (us)(v0[j] & 0xffff);
            Vs[e1 + kv]       = (us)(v0[j] >> 16);
            Vs[e0 + 128 + kv] = (us)(v1[j] & 0xffff);
            Vs[e1 + 128 + kv] = (us)(v1[j] >> 16);
        }
    }
    u32x4 qraw = {0u, 0u, 0u, 0u};
    if (w < 7) {
        const int l = w * 16 + l15;
        if (l < 100)
            qraw = *reinterpret_cast<const u32x4*>(
                Qb + ((size_t)((e * 100 + l) * 16 + b)) * 256 + h * 32 + quad * 8);
    }
    const bf16x8 qf = __builtin_bit_cast(bf16x8, qraw);

    __syncthreads();

    if (w >= 7) return;

    const f32x4 zacc = {};
    f32x4 o0 = {}, o1 = {};
    float lsum = 0.0f;

    for (int c = 0; c < 8; ++c) {
        bf16x8 kf0 = ld_bf8(&Ks[(c * 32 + l15) * 32 + quad * 8]);
        bf16x8 kf1 = ld_bf8(&Ks[(c * 32 + 16 + l15) * 32 + quad * 8]);
        f32x4 s0 = __builtin_amdgcn_mfma_f32_16x16x32_bf16(kf0, qf, zacc, 0, 0, 0);
        f32x4 s1 = __builtin_amdgcn_mfma_f32_16x16x32_bf16(kf1, qf, zacc, 0, 0, 0);
        float p0[4], p1[4];
#pragma unroll
        for (int r = 0; r < 4; ++r) {
            p0[r] = __expf(s0[r]);
            p1[r] = __expf(s1[r]);
            lsum += p0[r] + p1[r];
        }
        u32x2 w0, w1;
        w0[0] = (unsigned)f2bf(p0[0]) | ((unsigned)f2bf(p0[1]) << 16);
        w0[1] = (unsigned)f2bf(p0[2]) | ((unsigned)f2bf(p0[3]) << 16);
        w1[0] = (unsigned)f2bf(p1[0]) | ((unsigned)f2bf(p1[1]) << 16);
        w1[1] = (unsigned)f2bf(p1[2]) | ((unsigned)f2bf(p1[3]) << 16);
        *reinterpret_cast<u32x2*>(&Ps[w][l15 * 40 + quad * 4])      = w0;
        *reinterpret_cast<u32x2*>(&Ps[w][l15 * 40 + 16 + quad * 4]) = w1;
        bf16x8 pf  = ld_bf8(&Ps[w][l15 * 40 + quad * 8]);
        bf16x8 vf0 = ld_bf8(&Vs[vrow(l15) + c * 32 + quad * 8]);
        bf16x8 vf1 = ld_bf8(&Vs[vrow(16 + l15) + c * 32 + quad * 8]);
        o0 = __builtin_amdgcn_mfma_f32_16x16x32_bf16(pf, vf0, o0, 0, 0, 0);
        o1 = __builtin_amdgcn_mfma_f32_16x16x32_bf16(pf, vf1, o1, 0, 0, 0);
    }

    lsum += __shfl_xor(lsum, 16, 64);
    lsum += __shfl_xor(lsum, 32, 64);

#pragma unroll
    for (int r = 0; r < 4; ++r) {
        const int row = w * 16 + quad * 4 + r;
        if (row < 100) {
            const size_t o = (((size_t)((s * 5 + e) * 100 + row)) * 16 + b) * 256 + h * 32;
            PO[o + l15]      = f2bf(o0[r]);
            PO[o + 16 + l15] = f2bf(o1[r]);
        }
    }
    const int q = w * 16 + l15;
    if (quad == 0 && q < 100)
        PL[((((size_t)s * 5 + e) * 16 + b) * 8 + h) * 128 + q] = lsum;
}

// ---------------- combine partials -> CTX bf16 -----------------------------
__launch_bounds__(256)
__global__ void combine(const us* __restrict__ PO, const float* __restrict__ PL,
                        us* __restrict__ CTX)
{
    const int blk = blockIdx.x;
    const int e   = blk / 1600;
    const int rem = blk - e * 1600;
    const int row = rem >> 4;
    const int b   = rem & 15;
    const int d   = threadIdx.x;
    const int h   = d >> 5;
    float O = 0.0f, L = 0.0f;
#pragma unroll
    for (int s = 0; s < 4; ++s) {
        O += bf2f(PO[(((size_t)((s * 5 + e) * 100 + row)) * 16 + b) * 256 + d]);
        L += PL[((((size_t)s * 5 + e) * 16 + b) * 8 + h) * 128 + row];
    }
    CTX[(((size_t)(e * 100 + row)) * 16 + b) * 256 + d] = f2bf(O / L);
}

// ---------------- gate + mix + residual + LayerNorm ------------------------
__launch_bounds__(256)
__global__ void finalize(const float* __restrict__ tgt, const float* __restrict__ w_gate,
                         const float* __restrict__ b_gate, const float* __restrict__ OUTf,
                         const float* __restrict__ gamma, const float* __restrict__ beta,
                         float* __restrict__ out)
{
    const int row = blockIdx.x;
    const int d = threadIdx.x;
    __shared__ float red[4];
    const float t = tgt[(size_t)row * 256 + d];

    float g[5];
#pragma unroll
    for (int e = 0; e < 5; ++e) {
        float part = t * w_gate[e * 256 + d];
#pragma unroll
        for (int off = 32; off >= 1; off >>= 1) part += __shfl_xor(part, off, 64);
        if ((d & 63) == 0) red[d >> 6] = part;
        __syncthreads();
        g[e] = red[0] + red[1] + red[2] + red[3] + b_gate[e];
        __syncthreads();
    }
    float mx = g[0];
#pragma unroll
    for (int e = 1; e < 5; ++e) mx = fmaxf(mx, g[e]);
    float sm = 0.0f;
#pragma unroll
    for (int e = 0; e < 5; ++e) { g[e] = __expf(g[e] - mx); sm += g[e]; }
    const float invs = 1.0f / sm;

    float mo = 0.0f;
#pragma unroll
    for (int e = 0; e < 5; ++e)
        mo += g[e] * invs * OUTf[((size_t)e * 1600 + row) * 256 + d];
    const float x = t + mo;

    float part = x;
#pragma unroll
    for (int off = 32; off >= 1; off >>= 1) part += __shfl_xor(part, off, 64);
    if ((d & 63) == 0) red[d >> 6] = part;
    __syncthreads();
    const float mean = (red[0] + red[1] + red[2] + red[3]) * (1.0f / 256.0f);
    __syncthreads();

    const float diff = x - mean;
    part = diff * diff;
#pragma unroll
    for (int off = 32; off >= 1; off >>= 1) part += __shfl_xor(part, off, 64);
    if ((d & 63) == 0) red[d >> 6] = part;
    __syncthreads();
    const float var = (red[0] + red[1] + red[2] + red[3]) * (1.0f / 256.0f);

    out[(size_t)row * 256 + d] = diff * rsqrtf(var + 1e-5f) * gamma[d] + beta[d];
}

// ---------------------------------------------------------------------------
extern "C" void kernel_launch(void* const* d_in, const int* in_sizes, int n_in,
                              void* d_out, int out_size, void* d_ws, size_t ws_size,
                              hipStream_t stream)
{
    const float* tgt    = (const float*)d_in[0];
    const float* mem    = (const float*)d_in[1];
    const float* qpos   = (const float*)d_in[2];
    const float* pos    = (const float*)d_in[3];
    const float* w_in   = (const float*)d_in[4];
    const float* b_in   = (const float*)d_in[5];
    const float* w_out  = (const float*)d_in[6];
    const float* b_out  = (const float*)d_in[7];
    const float* w_gate = (const float*)d_in[8];
    const float* b_gate = (const float*)d_in[9];
    const float* ln_g   = (const float*)d_in[10];
    const float* ln_b   = (const float*)d_in[11];
    float* out = (float*)d_out;

    char* p = (char*)d_ws;
    auto alloc = [&](size_t n) { char* r = p; p += (n + 255) & ~(size_t)255; return r; };

    us* Aq   = (us*)alloc(409600ull * 2);       // dead after gemm_qkv_p
    us* Ak   = (us*)alloc(4194304ull * 2);      // dead after gemm_qkv_p
    us* Av   = (us*)alloc(4194304ull * 2);      // dead after gemm_qkv_p
    us* Wb   = (us*)alloc(983040ull * 2);
    us* WOb  = (us*)alloc(327680ull * 2);
    us* Qb   = (us*)alloc(5ull * 409600 * 2);
    us* Kb   = (us*)alloc(5ull * 4194304 * 2);
    us* Vb   = (us*)alloc(5ull * 4194304 * 2);
    us* CTXb = (us*)alloc(5ull * 409600 * 2);
    float* OUTf = (float*)alloc(5ull * 409600 * 4);
    // Attention partials alias the dead cvt region (Aq..Av)
    us*    PO = (us*)d_ws;                          // [4][5][100][16][256] bf16
    float* PL = (float*)((char*)d_ws + 16384000);   // [4*5*16*8][128] f32

    cvt_all<<<5776, 256, 0, stream>>>(tgt, qpos, mem, pos, w_in, w_out,
                                      Aq, Ak, Av, Wb, WOb);

    gemm_qkv_p<<<260, 256, 0, stream>>>(Aq, Ak, Av, Wb, b_in, Qb, Kb, Vb);

    attn<<<dim3(8, 80, 4), 512, 0, stream>>>(Qb, Kb, Vb, PO, PL);

    combine<<<8000, 256, 0, stream>>>(PO, PL, CTXb);

    gemm_o<<<dim3(13, 2, 5), 256, 0, stream>>>(CTXb, WOb, b_out, OUTf);

    finalize<<<1600, 256, 0, stream>>>(tgt, w_gate, b_gate, OUTf, ln_g, ln_b, out);
}